// Round 1
// baseline (9621.328 us; speedup 1.0000x reference)
//
#include <hip/hip_runtime.h>
#include <hip/hip_bf16.h>

// ---------------- ViT-B/16 forward, MI355X round 0 ----------------
// B=32, S=197 (padded to 208), D=768, H=12, DK=64, MLP=3072, DEPTH=12.
// All matmuls: mfma_f32_16x16x32_bf16, fp32 accum. Residual stream fp32.

typedef __attribute__((ext_vector_type(8))) short short8;
typedef __attribute__((ext_vector_type(4))) float f32x4;

#define MFMA16(a, b, c) __builtin_amdgcn_mfma_f32_16x16x32_bf16(a, b, c, 0, 0, 0)

#define BATCH 32
#define SEQ 197
#define SPAD 208          // 13 * 16
#define DIM 768
#define HEADS 12
#define DKH 64
#define MLPD 3072
#define NCLS 1000
#define NPATCH 196
#define PDIM 768
#define ROWS (BATCH * SPAD)   // 6656 = 52 * 128

static __device__ __forceinline__ unsigned short f2bf(float f) {
    unsigned int u = __builtin_bit_cast(unsigned int, f);
    u += 0x7fffu + ((u >> 16) & 1u);             // RNE
    return (unsigned short)(u >> 16);
}

// ---------------- patch extraction: x[B,3,224,224] -> patches bf16 [B,196,768]
// flat f = n*768+pd decomposes as (c,gy,gx,py,px) per the reference reshape.
__global__ __launch_bounds__(256) void patchify(const float* __restrict__ x,
                                                unsigned short* __restrict__ out) {
    int i = blockIdx.x * 256 + threadIdx.x;
    if (i >= BATCH * NPATCH * PDIM) return;
    int b = i / (NPATCH * PDIM);
    int f = i % (NPATCH * PDIM);
    int c = f / 50176, r = f % 50176;            // 50176 = 14*14*256
    int gy = r / 3584, r2 = r % 3584;            // 3584 = 14*256
    int gx = r2 >> 8, r3 = r2 & 255;
    int py = r3 >> 4, px = r3 & 15;
    float v = x[(((size_t)b * 3 + c) * 224 + gy * 16 + py) * 224 + gx * 16 + px];
    out[i] = f2bf(v);
}

// row 0 (cls + pos) and zero pad rows 197..207 of the fp32 residual stream
__global__ __launch_bounds__(256) void embed_misc(const float* __restrict__ cls,
                                                  const float* __restrict__ pos,
                                                  float* __restrict__ h) {
    int b = blockIdx.x, t = threadIdx.x;
    float* hb = h + (size_t)b * SPAD * DIM;
    for (int d = t; d < DIM; d += 256) hb[d] = cls[d] + pos[d];
    for (int i = t; i < (SPAD - SEQ) * DIM; i += 256) hb[SEQ * DIM + i] = 0.f;
}

// ---------------- generic GEMM: C[M,N] = A(bf16)[M,K] @ W(fp32->bf16)[K,N] + bias
// 128x128 tile, BK=32, 4 waves of 64x64 (4x4 16x16 frags).
// mode 0: out bf16   1: hbuf += (residual)   2: gelu -> bf16   3: patch embed (+pos)
__global__ __launch_bounds__(256) void gemm_bf16(
    const unsigned short* __restrict__ A, const float* __restrict__ W,
    const float* __restrict__ bias, int M, int N, int K, int mode,
    unsigned short* __restrict__ outb, float* __restrict__ outf,
    const float* __restrict__ pos) {
    __shared__ unsigned short Alds[128][40];   // +8 pad: 80B row stride, 2-way max
    __shared__ unsigned short Blds[128][40];   // stored n-major so B-frag k is contiguous
    const int tid = threadIdx.x;
    const int row0 = blockIdx.x * 128, col0 = blockIdx.y * 128;
    const int lane = tid & 63, wid = tid >> 6;
    const int wm = (wid >> 1) * 64, wn = (wid & 1) * 64;
    const int lr = lane & 15, lg = lane >> 4;

    f32x4 acc[4][4];
#pragma unroll
    for (int m = 0; m < 4; ++m)
#pragma unroll
        for (int n = 0; n < 4; ++n) acc[m][n] = (f32x4){0.f, 0.f, 0.f, 0.f};

    for (int k0 = 0; k0 < K; k0 += 32) {
        __syncthreads();
        // stage A: 128x32 bf16 (coalesced 16B)
#pragma unroll
        for (int j = 0; j < 2; ++j) {
            int idx = tid + j * 256;
            int r = idx >> 2, c = (idx & 3) << 3;
            *reinterpret_cast<uint4*>(&Alds[r][c]) =
                *reinterpret_cast<const uint4*>(&A[(size_t)(row0 + r) * K + k0 + c]);
        }
        // stage B: 32x128 fp32, convert, store transposed [n][k]
#pragma unroll
        for (int j = 0; j < 4; ++j) {
            int idx = tid + j * 256;
            int kk = idx >> 5, n = (idx & 31) << 2;
            float4 v = *reinterpret_cast<const float4*>(&W[(size_t)(k0 + kk) * N + col0 + n]);
            Blds[n + 0][kk] = f2bf(v.x);
            Blds[n + 1][kk] = f2bf(v.y);
            Blds[n + 2][kk] = f2bf(v.z);
            Blds[n + 3][kk] = f2bf(v.w);
        }
        __syncthreads();
        short8 af[4], bfr[4];
#pragma unroll
        for (int m = 0; m < 4; ++m)
            af[m] = *reinterpret_cast<const short8*>(&Alds[wm + m * 16 + lr][lg << 3]);
#pragma unroll
        for (int n = 0; n < 4; ++n)
            bfr[n] = *reinterpret_cast<const short8*>(&Blds[wn + n * 16 + lr][lg << 3]);
#pragma unroll
        for (int m = 0; m < 4; ++m)
#pragma unroll
            for (int n = 0; n < 4; ++n) acc[m][n] = MFMA16(af[m], bfr[n], acc[m][n]);
    }
    // epilogue — C/D layout: col = lane&15, row = (lane>>4)*4 + reg (m89-verified)
#pragma unroll
    for (int m = 0; m < 4; ++m) {
#pragma unroll
        for (int n = 0; n < 4; ++n) {
            int gcol = col0 + wn + n * 16 + lr;
            float bv = bias ? bias[gcol] : 0.f;
#pragma unroll
            for (int i = 0; i < 4; ++i) {
                int grow = row0 + wm + m * 16 + lg * 4 + i;
                float v = acc[m][n][i] + bv;
                if (mode == 0) {
                    outb[(size_t)grow * N + gcol] = f2bf(v);
                } else if (mode == 1) {
                    size_t o = (size_t)grow * N + gcol;
                    outf[o] += v;
                } else if (mode == 2) {
                    v = 0.5f * v * (1.f + erff(v * 0.70710678118654752f));
                    outb[(size_t)grow * N + gcol] = f2bf(v);
                } else {  // mode 3: patch embed, rows map to h[b, 1+n, :] with pos add
                    int pb = grow / NPATCH, pn = grow % NPATCH;
                    size_t o = ((size_t)pb * SPAD + 1 + pn) * DIM + gcol;
                    outf[o] = v + pos[(size_t)(1 + pn) * DIM + gcol];
                }
            }
        }
    }
}

// ---------------- LayerNorm fp32 -> bf16, one 256-thread block per row (D=768)
__global__ __launch_bounds__(256) void ln_bf16(const float* __restrict__ x,
                                               const float* __restrict__ g,
                                               const float* __restrict__ b,
                                               unsigned short* __restrict__ y) {
    __shared__ float red[8];
    int row = blockIdx.x, t = threadIdx.x;
    const float* xr = x + (size_t)row * DIM;
    float v0 = xr[t], v1 = xr[t + 256], v2 = xr[t + 512];
    float s = v0 + v1 + v2, sq = v0 * v0 + v1 * v1 + v2 * v2;
#pragma unroll
    for (int off = 1; off < 64; off <<= 1) {
        s += __shfl_xor(s, off);
        sq += __shfl_xor(sq, off);
    }
    if ((t & 63) == 0) { red[t >> 6] = s; red[4 + (t >> 6)] = sq; }
    __syncthreads();
    s = red[0] + red[1] + red[2] + red[3];
    sq = red[4] + red[5] + red[6] + red[7];
    float mu = s * (1.f / 768.f);
    float var = fmaxf(sq * (1.f / 768.f) - mu * mu, 0.f);
    float rs = rsqrtf(var + 1e-5f);
    unsigned short* yr = y + (size_t)row * DIM;
    yr[t]       = f2bf((v0 - mu) * rs * g[t] + b[t]);
    yr[t + 256] = f2bf((v1 - mu) * rs * g[t + 256] + b[t + 256]);
    yr[t + 512] = f2bf((v2 - mu) * rs * g[t + 512] + b[t + 512]);
}

// ---------------- attention scores+softmax: one wave per (q-tile, head, batch)
// P[b,h,208,224] bf16, cols>=197 masked to 0, cols 208..223 zeroed for PV frags.
__global__ __launch_bounds__(64) void attn_scores(const unsigned short* __restrict__ q,
                                                  const unsigned short* __restrict__ k,
                                                  unsigned short* __restrict__ p) {
    int qt = blockIdx.x, h = blockIdx.y, b = blockIdx.z;
    int lane = threadIdx.x, lr = lane & 15, lg = lane >> 4;
    size_t qoff = ((size_t)b * SPAD + qt * 16 + lr) * DIM + h * DKH + lg * 8;
    short8 qf0 = *reinterpret_cast<const short8*>(&q[qoff]);
    short8 qf1 = *reinterpret_cast<const short8*>(&q[qoff + 32]);
    f32x4 acc[13];
#pragma unroll
    for (int kt = 0; kt < 13; ++kt) {
        size_t koff = ((size_t)b * SPAD + kt * 16 + lr) * DIM + h * DKH + lg * 8;
        short8 kf0 = *reinterpret_cast<const short8*>(&k[koff]);
        short8 kf1 = *reinterpret_cast<const short8*>(&k[koff + 32]);
        f32x4 a = (f32x4){0.f, 0.f, 0.f, 0.f};
        a = MFMA16(qf0, kf0, a);
        a = MFMA16(qf1, kf1, a);
        acc[kt] = a;
    }
#pragma unroll
    for (int kt = 0; kt < 13; ++kt)
#pragma unroll
        for (int r = 0; r < 4; ++r) acc[kt][r] *= 0.125f;   // 1/sqrt(64)
    if (lr >= 5) {                                           // tokens 192+lr >= 197
#pragma unroll
        for (int r = 0; r < 4; ++r) acc[12][r] = -1e30f;
    }
    float mx[4] = {-1e30f, -1e30f, -1e30f, -1e30f};
#pragma unroll
    for (int kt = 0; kt < 13; ++kt)
#pragma unroll
        for (int r = 0; r < 4; ++r) mx[r] = fmaxf(mx[r], acc[kt][r]);
#pragma unroll
    for (int r = 0; r < 4; ++r) {
        mx[r] = fmaxf(mx[r], __shfl_xor(mx[r], 1));
        mx[r] = fmaxf(mx[r], __shfl_xor(mx[r], 2));
        mx[r] = fmaxf(mx[r], __shfl_xor(mx[r], 4));
        mx[r] = fmaxf(mx[r], __shfl_xor(mx[r], 8));
    }
    float sm[4] = {0.f, 0.f, 0.f, 0.f};
#pragma unroll
    for (int kt = 0; kt < 13; ++kt)
#pragma unroll
        for (int r = 0; r < 4; ++r) {
            float e = __expf(acc[kt][r] - mx[r]);
            acc[kt][r] = e;
            sm[r] += e;
        }
#pragma unroll
    for (int r = 0; r < 4; ++r) {
        sm[r] += __shfl_xor(sm[r], 1);
        sm[r] += __shfl_xor(sm[r], 2);
        sm[r] += __shfl_xor(sm[r], 4);
        sm[r] += __shfl_xor(sm[r], 8);
    }
    size_t pbase = ((size_t)(b * HEADS + h) * SPAD + qt * 16 + lg * 4) * 224;
#pragma unroll
    for (int r = 0; r < 4; ++r) {
        float inv = 1.f / sm[r];
        size_t rowo = pbase + (size_t)r * 224;
#pragma unroll
        for (int kt = 0; kt < 13; ++kt) p[rowo + kt * 16 + lr] = f2bf(acc[kt][r] * inv);
        p[rowo + 208 + lr] = 0;   // zero pad cols 208..223
    }
}

// ---------------- PV: att[b,s,h*64+d] = P @ V, V transposed in LDS so k is contiguous
__global__ __launch_bounds__(256) void attn_pv(const unsigned short* __restrict__ p,
                                               const unsigned short* __restrict__ v,
                                               unsigned short* __restrict__ att) {
    __shared__ unsigned short Vlds[64][232];   // [d][k], 464B stride: <=2-way banks
    int h = blockIdx.x, b = blockIdx.y, tid = threadIdx.x;
    for (int idx = tid; idx < SPAD * 8; idx += 256) {
        int s = idx >> 3, dc = (idx & 7) << 3;
        uint4 w = *reinterpret_cast<const uint4*>(&v[((size_t)b * SPAD + s) * DIM + h * DKH + dc]);
        const unsigned short* pe = reinterpret_cast<const unsigned short*>(&w);
#pragma unroll
        for (int i = 0; i < 8; ++i) Vlds[dc + i][s] = pe[i];
    }
    for (int i = tid; i < 64 * 24; i += 256) Vlds[i / 24][208 + (i % 24)] = 0;
    __syncthreads();
    int wid = tid >> 6, lane = tid & 63, lr = lane & 15, lg = lane >> 4;
    for (int qt = wid; qt < 13; qt += 4) {
        short8 af[7];
        size_t prow = ((size_t)(b * HEADS + h) * SPAD + qt * 16 + lr) * 224;
#pragma unroll
        for (int kk = 0; kk < 7; ++kk)
            af[kk] = *reinterpret_cast<const short8*>(&p[prow + kk * 32 + lg * 8]);
#pragma unroll
        for (int dt = 0; dt < 4; ++dt) {
            f32x4 a = (f32x4){0.f, 0.f, 0.f, 0.f};
#pragma unroll
            for (int kk = 0; kk < 7; ++kk) {
                short8 bfr = *reinterpret_cast<const short8*>(&Vlds[dt * 16 + lr][kk * 32 + lg * 8]);
                a = MFMA16(af[kk], bfr, a);
            }
#pragma unroll
            for (int i = 0; i < 4; ++i) {
                int s = qt * 16 + lg * 4 + i;
                att[((size_t)b * SPAD + s) * DIM + h * DKH + dt * 16 + lr] = f2bf(a[i]);
            }
        }
    }
}

// ---------------- final LN (cls row) + fp32 head GEMM [32,768]@[768,1000]
__global__ __launch_bounds__(256) void head_kernel(const float* __restrict__ hb,
                                                   const float* __restrict__ g,
                                                   const float* __restrict__ bb,
                                                   const float* __restrict__ hw,
                                                   const float* __restrict__ hbi,
                                                   float* __restrict__ out) {
    __shared__ float rowv[768];
    __shared__ float red[8];
    int b = blockIdx.x, t = threadIdx.x;
    const float* xr = hb + (size_t)b * SPAD * DIM;
    float v0 = xr[t], v1 = xr[t + 256], v2 = xr[t + 512];
    float s = v0 + v1 + v2, sq = v0 * v0 + v1 * v1 + v2 * v2;
#pragma unroll
    for (int off = 1; off < 64; off <<= 1) {
        s += __shfl_xor(s, off);
        sq += __shfl_xor(sq, off);
    }
    if ((t & 63) == 0) { red[t >> 6] = s; red[4 + (t >> 6)] = sq; }
    __syncthreads();
    s = red[0] + red[1] + red[2] + red[3];
    sq = red[4] + red[5] + red[6] + red[7];
    float mu = s * (1.f / 768.f);
    float var = fmaxf(sq * (1.f / 768.f) - mu * mu, 0.f);
    float rs = rsqrtf(var + 1e-5f);
    rowv[t]       = (v0 - mu) * rs * g[t] + bb[t];
    rowv[t + 256] = (v1 - mu) * rs * g[t + 256] + bb[t + 256];
    rowv[t + 512] = (v2 - mu) * rs * g[t + 512] + bb[t + 512];
    __syncthreads();
    for (int n = t; n < NCLS; n += 256) {
        float a = hbi[n];
        for (int k2 = 0; k2 < DIM; ++k2) a = fmaf(rowv[k2], hw[(size_t)k2 * NCLS + n], a);
        out[(size_t)b * NCLS + n] = a;
    }
}

extern "C" void kernel_launch(void* const* d_in, const int* in_sizes, int n_in,
                              void* d_out, int out_size, void* d_ws, size_t ws_size,
                              hipStream_t stream) {
    const float* x      = (const float*)d_in[0];
    const float* patchW = (const float*)d_in[1];
    const float* patchB = (const float*)d_in[2];
    const float* clstok = (const float*)d_in[3];
    const float* pose   = (const float*)d_in[4];
    const float* Wq = (const float*)d_in[5];
    const float* bq = (const float*)d_in[6];
    const float* Wk = (const float*)d_in[7];
    const float* bk = (const float*)d_in[8];
    const float* Wv = (const float*)d_in[9];
    const float* bv = (const float*)d_in[10];
    const float* Wo = (const float*)d_in[11];
    const float* bo = (const float*)d_in[12];
    const float* ln1g = (const float*)d_in[13];
    const float* ln1b = (const float*)d_in[14];
    const float* ln2g = (const float*)d_in[15];
    const float* ln2b = (const float*)d_in[16];
    const float* W1 = (const float*)d_in[17];
    const float* b1 = (const float*)d_in[18];
    const float* W2 = (const float*)d_in[19];
    const float* b2 = (const float*)d_in[20];
    const float* lnpg = (const float*)d_in[21];
    const float* lnpb = (const float*)d_in[22];
    const float* headW = (const float*)d_in[23];
    const float* headB = (const float*)d_in[24];
    float* out = (float*)d_out;

    // workspace layout (112.5 MB total):
    //   hbuf fp32 [6656,768] | y,q,k,v,att bf16 [6656,768] | m1 region 40.9MB
    //   m1 region time-shares: patches bf16 (embed), P bf16 [32,12,208,224] (attn),
    //   MLP intermediate bf16 [6656,3072].
    constexpr size_t SZ_H  = (size_t)ROWS * DIM * 4;   // 20,447,232
    constexpr size_t SZ_BF = (size_t)ROWS * DIM * 2;   // 10,223,616
    char* w = (char*)d_ws;
    float* hbuf           = (float*)w;
    unsigned short* ybuf  = (unsigned short*)(w + SZ_H);
    unsigned short* qbuf  = (unsigned short*)(w + SZ_H + 1 * SZ_BF);
    unsigned short* kbuf  = (unsigned short*)(w + SZ_H + 2 * SZ_BF);
    unsigned short* vbuf  = (unsigned short*)(w + SZ_H + 3 * SZ_BF);
    unsigned short* attb  = (unsigned short*)(w + SZ_H + 4 * SZ_BF);
    unsigned short* m1buf = (unsigned short*)(w + SZ_H + 5 * SZ_BF);
    unsigned short* pbuf    = m1buf;
    unsigned short* patches = m1buf;

    // patch embed
    patchify<<<dim3((BATCH * NPATCH * PDIM + 255) / 256), 256, 0, stream>>>(x, patches);
    embed_misc<<<dim3(BATCH), 256, 0, stream>>>(clstok, pose, hbuf);
    gemm_bf16<<<dim3(49, 6), 256, 0, stream>>>(patches, patchW, patchB,
                                               BATCH * NPATCH, DIM, PDIM, 3,
                                               nullptr, hbuf, pose);

    for (int i = 0; i < 12; ++i) {
        const size_t wo = (size_t)i * DIM * DIM;
        ln_bf16<<<dim3(ROWS), 256, 0, stream>>>(hbuf, ln1g + i * DIM, ln1b + i * DIM, ybuf);
        gemm_bf16<<<dim3(52, 6), 256, 0, stream>>>(ybuf, Wq + wo, bq + i * DIM,
                                                   ROWS, DIM, DIM, 0, qbuf, nullptr, nullptr);
        gemm_bf16<<<dim3(52, 6), 256, 0, stream>>>(ybuf, Wk + wo, bk + i * DIM,
                                                   ROWS, DIM, DIM, 0, kbuf, nullptr, nullptr);
        gemm_bf16<<<dim3(52, 6), 256, 0, stream>>>(ybuf, Wv + wo, bv + i * DIM,
                                                   ROWS, DIM, DIM, 0, vbuf, nullptr, nullptr);
        attn_scores<<<dim3(13, HEADS, BATCH), 64, 0, stream>>>(qbuf, kbuf, pbuf);
        attn_pv<<<dim3(HEADS, BATCH), 256, 0, stream>>>(pbuf, vbuf, attb);
        gemm_bf16<<<dim3(52, 6), 256, 0, stream>>>(attb, Wo + wo, bo + i * DIM,
                                                   ROWS, DIM, DIM, 1, nullptr, hbuf, nullptr);
        ln_bf16<<<dim3(ROWS), 256, 0, stream>>>(hbuf, ln2g + i * DIM, ln2b + i * DIM, ybuf);
        gemm_bf16<<<dim3(52, 24), 256, 0, stream>>>(ybuf, W1 + (size_t)i * DIM * MLPD,
                                                    b1 + i * MLPD, ROWS, MLPD, DIM, 2,
                                                    m1buf, nullptr, nullptr);
        gemm_bf16<<<dim3(52, 6), 256, 0, stream>>>(m1buf, W2 + (size_t)i * DIM * MLPD,
                                                   b2 + i * DIM, ROWS, DIM, MLPD, 1,
                                                   nullptr, hbuf, nullptr);
    }
    head_kernel<<<dim3(BATCH), 256, 0, stream>>>(hbuf, lnpg, lnpb, headW, headB, out);
}

// Round 2
// 3740.324 us; speedup vs baseline: 2.5723x; 2.5723x over previous
//
#include <hip/hip_runtime.h>
#include <hip/hip_bf16.h>

// ---------------- ViT-B/16 forward, MI355X round 2 ----------------
// Changes vs round 1:
//  - per-layer weight transpose+convert fp32[K,N] -> bf16 [N,K] (one kernel)
//  - GEMM: m97 structure — global_load_lds(16B) staging, linear LDS, 2-barrier
//  - QKV fused into one N=2304 GEMM; BM=64 tiles for N=768 GEMMs (occupancy)

typedef __attribute__((ext_vector_type(8))) short short8;
typedef __attribute__((ext_vector_type(4))) float f32x4;
typedef __attribute__((ext_vector_type(4))) unsigned short us4;

#define MFMA16(a, b, c) __builtin_amdgcn_mfma_f32_16x16x32_bf16(a, b, c, 0, 0, 0)

#define BATCH 32
#define SEQ 197
#define SPAD 208          // 13 * 16
#define DIM 768
#define HEADS 12
#define DKH 64
#define MLPD 3072
#define NCLS 1000
#define NPATCH 196
#define PDIM 768
#define QKVD 2304
#define ROWS (BATCH * SPAD)   // 6656 = 52*128 = 104*64

static __device__ __forceinline__ unsigned short f2bf(float f) {
    unsigned int u = __builtin_bit_cast(unsigned int, f);
    u += 0x7fffu + ((u >> 16) & 1u);             // RNE
    return (unsigned short)(u >> 16);
}

__device__ __forceinline__ void gload16(const void* g, void* l) {
    __builtin_amdgcn_global_load_lds(
        (const __attribute__((address_space(1))) void*)g,
        (__attribute__((address_space(3))) void*)l, 16, 0, 0);
}

// ---------------- patch extraction: x[B,3,224,224] -> patches bf16 [B,196,768]
__global__ __launch_bounds__(256) void patchify(const float* __restrict__ x,
                                                unsigned short* __restrict__ out) {
    int i = blockIdx.x * 256 + threadIdx.x;
    if (i >= BATCH * NPATCH * PDIM) return;
    int b = i / (NPATCH * PDIM);
    int f = i % (NPATCH * PDIM);
    int c = f / 50176, r = f % 50176;
    int gy = r / 3584, r2 = r % 3584;
    int gx = r2 >> 8, r3 = r2 & 255;
    int py = r3 >> 4, px = r3 & 15;
    float v = x[(((size_t)b * 3 + c) * 224 + gy * 16 + py) * 224 + gx * 16 + px];
    out[i] = f2bf(v);
}

// row 0 (cls + pos) and zero pad rows 197..207 of the fp32 residual stream
__global__ __launch_bounds__(256) void embed_misc(const float* __restrict__ cls,
                                                  const float* __restrict__ pos,
                                                  float* __restrict__ h) {
    int b = blockIdx.x, t = threadIdx.x;
    float* hb = h + (size_t)b * SPAD * DIM;
    for (int d = t; d < DIM; d += 256) hb[d] = cls[d] + pos[d];
    for (int i = t; i < (SPAD - SEQ) * DIM; i += 256) hb[SEQ * DIM + i] = 0.f;
}

// ---------------- generic transpose-convert: src fp32 [K,N] -> dst bf16 [N,K]
__global__ __launch_bounds__(256) void tconv(const float* __restrict__ src,
                                             unsigned short* __restrict__ dst,
                                             int K, int N) {
    __shared__ float tile[32][33];
    int tn = blockIdx.x, tk = blockIdx.y;
    int t = threadIdx.x, r = t >> 3, c4 = (t & 7) << 2;
    float4 v = *reinterpret_cast<const float4*>(&src[(size_t)(tk * 32 + r) * N + tn * 32 + c4]);
    tile[r][c4 + 0] = v.x; tile[r][c4 + 1] = v.y;
    tile[r][c4 + 2] = v.z; tile[r][c4 + 3] = v.w;
    __syncthreads();
    us4 o = { f2bf(tile[c4 + 0][r]), f2bf(tile[c4 + 1][r]),
              f2bf(tile[c4 + 2][r]), f2bf(tile[c4 + 3][r]) };
    *reinterpret_cast<us4*>(&dst[(size_t)(tn * 32 + r) * K + tk * 32 + c4]) = o;
}

// ---------------- fused per-layer weight conversion into wT region:
//   [0)        qkvT  [2304][768]
//   [1769472)  oT    [768][768]
//   [2359296)  w1T   [3072][768]
//   [4718592)  w2T   [768][3072]   (total 7,077,888 elems)
__global__ __launch_bounds__(256) void wconvert(const float* __restrict__ q,
                                                const float* __restrict__ k,
                                                const float* __restrict__ v,
                                                const float* __restrict__ o,
                                                const float* __restrict__ w1,
                                                const float* __restrict__ w2,
                                                unsigned short* __restrict__ wT) {
    __shared__ float tile[32][33];
    int tb = blockIdx.x;
    const float* src; unsigned short* dst; int K, N;
    if (tb < 2304) {
        K = 768; N = 768;
        int m = tb / 576; tb -= m * 576;
        src = (m == 0) ? q : (m == 1) ? k : (m == 2) ? v : o;
        dst = wT + (m < 3 ? (size_t)m * 589824 : (size_t)1769472);
    } else if (tb < 4608) {
        tb -= 2304; K = 768; N = 3072; src = w1; dst = wT + 2359296;
    } else {
        tb -= 4608; K = 3072; N = 768; src = w2; dst = wT + 4718592;
    }
    int TN = N >> 5;
    int tn = tb % TN, tk = tb / TN;
    int t = threadIdx.x, r = t >> 3, c4 = (t & 7) << 2;
    float4 vv = *reinterpret_cast<const float4*>(&src[(size_t)(tk * 32 + r) * N + tn * 32 + c4]);
    tile[r][c4 + 0] = vv.x; tile[r][c4 + 1] = vv.y;
    tile[r][c4 + 2] = vv.z; tile[r][c4 + 3] = vv.w;
    __syncthreads();
    us4 ov = { f2bf(tile[c4 + 0][r]), f2bf(tile[c4 + 1][r]),
               f2bf(tile[c4 + 2][r]), f2bf(tile[c4 + 3][r]) };
    *reinterpret_cast<us4*>(&dst[(size_t)(tn * 32 + r) * K + tk * 32 + c4]) = ov;
}

// pack per-layer qkv bias: bqkv[12][2304]
__global__ __launch_bounds__(256) void pack_bias(const float* __restrict__ bq,
                                                 const float* __restrict__ bk,
                                                 const float* __restrict__ bv,
                                                 float* __restrict__ dst) {
    int i = blockIdx.x * 256 + threadIdx.x;
    if (i >= 12 * QKVD) return;
    int l = i / QKVD, c = i % QKVD;
    float v = (c < 768) ? bq[l * 768 + c]
            : (c < 1536) ? bk[l * 768 + c - 768]
                         : bv[l * 768 + c - 1536];
    dst[i] = v;
}

// ---------------- GEMM (m97 structure): C[M,N] = A bf16[M,K] @ Bt bf16[N,K]^T + bias
// BM x 128 tile, BK=32, 4 waves; global_load_lds(16B) staging, linear LDS.
// mode 0: out bf16   1: outf += (residual)   2: gelu -> bf16   3: patch embed (+pos)
template <int BM>
__global__ __launch_bounds__(256) void gemm_tn(
    const unsigned short* __restrict__ A, const unsigned short* __restrict__ Bt,
    const float* __restrict__ bias, int M, int N, int K, int mode,
    unsigned short* __restrict__ outb, float* __restrict__ outf,
    const float* __restrict__ pos) {
    constexpr int MFRAG = BM / 32;        // 4 (BM=128) or 2 (BM=64)
    constexpr int ACH = BM / 16;          // 1KB staging chunks in A tile
    constexpr int CPW = (ACH + 8) / 4;    // chunks per wave (A+B total)
    __shared__ unsigned short Alds[BM * 32];
    __shared__ unsigned short Blds[128 * 32];
    const int tid = threadIdx.x, lane = tid & 63, wid = tid >> 6;
    const int row0 = blockIdx.x * BM, col0 = blockIdx.y * 128;
    const int wm = (wid >> 1) * (BM / 2), wn = (wid & 1) * 64;
    const int lr = lane & 15, lg = lane >> 4;
    const char* Ab = (const char*)A;
    const char* Bb = (const char*)Bt;

    f32x4 acc[MFRAG][4];
#pragma unroll
    for (int m = 0; m < MFRAG; ++m)
#pragma unroll
        for (int n = 0; n < 4; ++n) acc[m][n] = (f32x4){0.f, 0.f, 0.f, 0.f};

    for (int k0 = 0; k0 < K; k0 += 32) {
        __syncthreads();
#pragma unroll
        for (int j = 0; j < CPW; ++j) {
            const int cc = wid * CPW + j;
            if (cc < ACH) {
                const int bo = cc * 1024 + lane * 16;
                gload16(Ab + (((size_t)(row0 + (bo >> 6)) * K + k0) << 1) + (bo & 63),
                        (char*)Alds + cc * 1024);
            } else {
                const int bo = (cc - ACH) * 1024 + lane * 16;
                gload16(Bb + (((size_t)(col0 + (bo >> 6)) * K + k0) << 1) + (bo & 63),
                        (char*)Blds + (cc - ACH) * 1024);
            }
        }
        __syncthreads();
        short8 af[MFRAG], bfr[4];
#pragma unroll
        for (int m = 0; m < MFRAG; ++m)
            af[m] = *reinterpret_cast<const short8*>(&Alds[(wm + m * 16 + lr) * 32 + (lg << 3)]);
#pragma unroll
        for (int n = 0; n < 4; ++n)
            bfr[n] = *reinterpret_cast<const short8*>(&Blds[(wn + n * 16 + lr) * 32 + (lg << 3)]);
#pragma unroll
        for (int m = 0; m < MFRAG; ++m)
#pragma unroll
            for (int n = 0; n < 4; ++n) acc[m][n] = MFMA16(af[m], bfr[n], acc[m][n]);
    }
    // epilogue — C/D layout: col = lane&15, row = (lane>>4)*4 + reg
#pragma unroll
    for (int m = 0; m < MFRAG; ++m) {
#pragma unroll
        for (int n = 0; n < 4; ++n) {
            int gcol = col0 + wn + n * 16 + lr;
            float bv = bias ? bias[gcol] : 0.f;
#pragma unroll
            for (int i = 0; i < 4; ++i) {
                int grow = row0 + wm + m * 16 + lg * 4 + i;
                float v = acc[m][n][i] + bv;
                if (mode == 0) {
                    outb[(size_t)grow * N + gcol] = f2bf(v);
                } else if (mode == 1) {
                    outf[(size_t)grow * N + gcol] += v;
                } else if (mode == 2) {
                    v = 0.5f * v * (1.f + erff(v * 0.70710678118654752f));
                    outb[(size_t)grow * N + gcol] = f2bf(v);
                } else {  // mode 3: patch embed rows -> h[b, 1+n, :] with pos add
                    int pb = grow / NPATCH, pn = grow % NPATCH;
                    size_t o = ((size_t)pb * SPAD + 1 + pn) * DIM + gcol;
                    outf[o] = v + pos[(size_t)(1 + pn) * DIM + gcol];
                }
            }
        }
    }
}

// ---------------- LayerNorm fp32 -> bf16, one block per row (D=768)
__global__ __launch_bounds__(256) void ln_bf16(const float* __restrict__ x,
                                               const float* __restrict__ g,
                                               const float* __restrict__ b,
                                               unsigned short* __restrict__ y) {
    __shared__ float red[8];
    int row = blockIdx.x, t = threadIdx.x;
    const float* xr = x + (size_t)row * DIM;
    float v0 = xr[t], v1 = xr[t + 256], v2 = xr[t + 512];
    float s = v0 + v1 + v2, sq = v0 * v0 + v1 * v1 + v2 * v2;
#pragma unroll
    for (int off = 1; off < 64; off <<= 1) {
        s += __shfl_xor(s, off);
        sq += __shfl_xor(sq, off);
    }
    if ((t & 63) == 0) { red[t >> 6] = s; red[4 + (t >> 6)] = sq; }
    __syncthreads();
    s = red[0] + red[1] + red[2] + red[3];
    sq = red[4] + red[5] + red[6] + red[7];
    float mu = s * (1.f / 768.f);
    float var = fmaxf(sq * (1.f / 768.f) - mu * mu, 0.f);
    float rs = rsqrtf(var + 1e-5f);
    unsigned short* yr = y + (size_t)row * DIM;
    yr[t]       = f2bf((v0 - mu) * rs * g[t] + b[t]);
    yr[t + 256] = f2bf((v1 - mu) * rs * g[t + 256] + b[t + 256]);
    yr[t + 512] = f2bf((v2 - mu) * rs * g[t + 512] + b[t + 512]);
}

// ---------------- attention scores+softmax: one wave per (q-tile, head, batch)
// reads fused qkv [ROWS, 2304]; P[b,h,208,224] bf16.
__global__ __launch_bounds__(64) void attn_scores(const unsigned short* __restrict__ qkv,
                                                  unsigned short* __restrict__ p) {
    int qt = blockIdx.x, h = blockIdx.y, b = blockIdx.z;
    int lane = threadIdx.x, lr = lane & 15, lg = lane >> 4;
    size_t qoff = ((size_t)b * SPAD + qt * 16 + lr) * QKVD + h * DKH + lg * 8;
    short8 qf0 = *reinterpret_cast<const short8*>(&qkv[qoff]);
    short8 qf1 = *reinterpret_cast<const short8*>(&qkv[qoff + 32]);
    f32x4 acc[13];
#pragma unroll
    for (int kt = 0; kt < 13; ++kt) {
        size_t koff = ((size_t)b * SPAD + kt * 16 + lr) * QKVD + 768 + h * DKH + lg * 8;
        short8 kf0 = *reinterpret_cast<const short8*>(&qkv[koff]);
        short8 kf1 = *reinterpret_cast<const short8*>(&qkv[koff + 32]);
        f32x4 a = (f32x4){0.f, 0.f, 0.f, 0.f};
        a = MFMA16(qf0, kf0, a);
        a = MFMA16(qf1, kf1, a);
        acc[kt] = a;
    }
#pragma unroll
    for (int kt = 0; kt < 13; ++kt)
#pragma unroll
        for (int r = 0; r < 4; ++r) acc[kt][r] *= 0.125f;
    if (lr >= 5) {
#pragma unroll
        for (int r = 0; r < 4; ++r) acc[12][r] = -1e30f;
    }
    float mx[4] = {-1e30f, -1e30f, -1e30f, -1e30f};
#pragma unroll
    for (int kt = 0; kt < 13; ++kt)
#pragma unroll
        for (int r = 0; r < 4; ++r) mx[r] = fmaxf(mx[r], acc[kt][r]);
#pragma unroll
    for (int r = 0; r < 4; ++r) {
        mx[r] = fmaxf(mx[r], __shfl_xor(mx[r], 1));
        mx[r] = fmaxf(mx[r], __shfl_xor(mx[r], 2));
        mx[r] = fmaxf(mx[r], __shfl_xor(mx[r], 4));
        mx[r] = fmaxf(mx[r], __shfl_xor(mx[r], 8));
    }
    float sm[4] = {0.f, 0.f, 0.f, 0.f};
#pragma unroll
    for (int kt = 0; kt < 13; ++kt)
#pragma unroll
        for (int r = 0; r < 4; ++r) {
            float e = __expf(acc[kt][r] - mx[r]);
            acc[kt][r] = e;
            sm[r] += e;
        }
#pragma unroll
    for (int r = 0; r < 4; ++r) {
        sm[r] += __shfl_xor(sm[r], 1);
        sm[r] += __shfl_xor(sm[r], 2);
        sm[r] += __shfl_xor(sm[r], 4);
        sm[r] += __shfl_xor(sm[r], 8);
    }
    size_t pbase = ((size_t)(b * HEADS + h) * SPAD + qt * 16 + lg * 4) * 224;
#pragma unroll
    for (int r = 0; r < 4; ++r) {
        float inv = 1.f / sm[r];
        size_t rowo = pbase + (size_t)r * 224;
#pragma unroll
        for (int kt = 0; kt < 13; ++kt) p[rowo + kt * 16 + lr] = f2bf(acc[kt][r] * inv);
        p[rowo + 208 + lr] = 0;
    }
}

// ---------------- PV: att[b,s, h*64+d] = P @ V ; V from fused qkv (col 1536+)
__global__ __launch_bounds__(256) void attn_pv(const unsigned short* __restrict__ p,
                                               const unsigned short* __restrict__ qkv,
                                               unsigned short* __restrict__ att) {
    __shared__ unsigned short Vlds[64][232];
    int h = blockIdx.x, b = blockIdx.y, tid = threadIdx.x;
    for (int idx = tid; idx < SPAD * 8; idx += 256) {
        int s = idx >> 3, dc = (idx & 7) << 3;
        uint4 w = *reinterpret_cast<const uint4*>(
            &qkv[((size_t)b * SPAD + s) * QKVD + 1536 + h * DKH + dc]);
        const unsigned short* pe = reinterpret_cast<const unsigned short*>(&w);
#pragma unroll
        for (int i = 0; i < 8; ++i) Vlds[dc + i][s] = pe[i];
    }
    for (int i = tid; i < 64 * 24; i += 256) Vlds[i / 24][208 + (i % 24)] = 0;
    __syncthreads();
    int wid = tid >> 6, lane = tid & 63, lr = lane & 15, lg = lane >> 4;
    for (int qt = wid; qt < 13; qt += 4) {
        short8 af[7];
        size_t prow = ((size_t)(b * HEADS + h) * SPAD + qt * 16 + lr) * 224;
#pragma unroll
        for (int kk = 0; kk < 7; ++kk)
            af[kk] = *reinterpret_cast<const short8*>(&p[prow + kk * 32 + lg * 8]);
#pragma unroll
        for (int dt = 0; dt < 4; ++dt) {
            f32x4 a = (f32x4){0.f, 0.f, 0.f, 0.f};
#pragma unroll
            for (int kk = 0; kk < 7; ++kk) {
                short8 bfr = *reinterpret_cast<const short8*>(&Vlds[dt * 16 + lr][kk * 32 + lg * 8]);
                a = MFMA16(af[kk], bfr, a);
            }
#pragma unroll
            for (int i = 0; i < 4; ++i) {
                int s = qt * 16 + lg * 4 + i;
                att[((size_t)b * SPAD + s) * DIM + h * DKH + dt * 16 + lr] = f2bf(a[i]);
            }
        }
    }
}

// ---------------- final LN (cls row) + fp32 head GEMM [32,768]@[768,1000]
__global__ __launch_bounds__(256) void head_kernel(const float* __restrict__ hb,
                                                   const float* __restrict__ g,
                                                   const float* __restrict__ bb,
                                                   const float* __restrict__ hw,
                                                   const float* __restrict__ hbi,
                                                   float* __restrict__ out) {
    __shared__ float rowv[768];
    __shared__ float red[8];
    int b = blockIdx.x, t = threadIdx.x;
    const float* xr = hb + (size_t)b * SPAD * DIM;
    float v0 = xr[t], v1 = xr[t + 256], v2 = xr[t + 512];
    float s = v0 + v1 + v2, sq = v0 * v0 + v1 * v1 + v2 * v2;
#pragma unroll
    for (int off = 1; off < 64; off <<= 1) {
        s += __shfl_xor(s, off);
        sq += __shfl_xor(sq, off);
    }
    if ((t & 63) == 0) { red[t >> 6] = s; red[4 + (t >> 6)] = sq; }
    __syncthreads();
    s = red[0] + red[1] + red[2] + red[3];
    sq = red[4] + red[5] + red[6] + red[7];
    float mu = s * (1.f / 768.f);
    float var = fmaxf(sq * (1.f / 768.f) - mu * mu, 0.f);
    float rs = rsqrtf(var + 1e-5f);
    rowv[t]       = (v0 - mu) * rs * g[t] + bb[t];
    rowv[t + 256] = (v1 - mu) * rs * g[t + 256] + bb[t + 256];
    rowv[t + 512] = (v2 - mu) * rs * g[t + 512] + bb[t + 512];
    __syncthreads();
    for (int n = t; n < NCLS; n += 256) {
        float a = hbi[n];
        for (int k2 = 0; k2 < DIM; ++k2) a = fmaf(rowv[k2], hw[(size_t)k2 * NCLS + n], a);
        out[(size_t)b * NCLS + n] = a;
    }
}

extern "C" void kernel_launch(void* const* d_in, const int* in_sizes, int n_in,
                              void* d_out, int out_size, void* d_ws, size_t ws_size,
                              hipStream_t stream) {
    const float* x      = (const float*)d_in[0];
    const float* patchW = (const float*)d_in[1];
    const float* patchB = (const float*)d_in[2];
    const float* clstok = (const float*)d_in[3];
    const float* pose   = (const float*)d_in[4];
    const float* Wq = (const float*)d_in[5];
    const float* bq = (const float*)d_in[6];
    const float* Wk = (const float*)d_in[7];
    const float* bk = (const float*)d_in[8];
    const float* Wv = (const float*)d_in[9];
    const float* bv = (const float*)d_in[10];
    const float* Wo = (const float*)d_in[11];
    const float* bo = (const float*)d_in[12];
    const float* ln1g = (const float*)d_in[13];
    const float* ln1b = (const float*)d_in[14];
    const float* ln2g = (const float*)d_in[15];
    const float* ln2b = (const float*)d_in[16];
    const float* W1 = (const float*)d_in[17];
    const float* b1 = (const float*)d_in[18];
    const float* W2 = (const float*)d_in[19];
    const float* b2 = (const float*)d_in[20];
    const float* lnpg = (const float*)d_in[21];
    const float* lnpb = (const float*)d_in[22];
    const float* headW = (const float*)d_in[23];
    const float* headB = (const float*)d_in[24];
    float* out = (float*)d_out;

    // workspace layout (~116.6 MB):
    constexpr size_t SZ_H   = (size_t)ROWS * DIM * 4;     // fp32 residual
    constexpr size_t SZ_QKV = (size_t)ROWS * QKVD * 2;    // fused qkv bf16
    constexpr size_t SZ_Y   = (size_t)ROWS * DIM * 2;     // ln out / att bf16
    constexpr size_t SZ_M1  = (size_t)ROWS * MLPD * 2;    // mlp mid / patches / P
    constexpr size_t SZ_WT  = (size_t)7077888 * 2;        // per-layer bf16 weightsT
    char* w = (char*)d_ws;
    float* hbuf            = (float*)w;
    unsigned short* qkvb   = (unsigned short*)(w + SZ_H);
    unsigned short* ybuf   = (unsigned short*)(w + SZ_H + SZ_QKV);
    unsigned short* m1buf  = (unsigned short*)(w + SZ_H + SZ_QKV + SZ_Y);
    unsigned short* wT     = (unsigned short*)(w + SZ_H + SZ_QKV + SZ_Y + SZ_M1);
    float* bqkv            = (float*)(w + SZ_H + SZ_QKV + SZ_Y + SZ_M1 + SZ_WT);
    unsigned short* pbuf    = m1buf;   // P [32,12,208,224] bf16 (38.5 MB < 40.9 MB)
    unsigned short* patches = m1buf;   // patches bf16 (9.6 MB)

    pack_bias<<<dim3(108), 256, 0, stream>>>(bq, bk, bv, bqkv);

    // patch embed: transpose patchW into wT, then GEMM
    tconv<<<dim3(24, 24), 256, 0, stream>>>(patchW, wT, PDIM, DIM);
    patchify<<<dim3((BATCH * NPATCH * PDIM + 255) / 256), 256, 0, stream>>>(x, patches);
    embed_misc<<<dim3(BATCH), 256, 0, stream>>>(clstok, pose, hbuf);
    gemm_tn<64><<<dim3(98, 6), 256, 0, stream>>>(patches, wT, patchB,
                                                 BATCH * NPATCH, DIM, PDIM, 3,
                                                 nullptr, hbuf, pose);

    for (int i = 0; i < 12; ++i) {
        const size_t wo = (size_t)i * DIM * DIM;
        const size_t wm = (size_t)i * DIM * MLPD;
        wconvert<<<dim3(6912), 256, 0, stream>>>(Wq + wo, Wk + wo, Wv + wo, Wo + wo,
                                                 W1 + wm, W2 + wm, wT);
        ln_bf16<<<dim3(ROWS), 256, 0, stream>>>(hbuf, ln1g + i * DIM, ln1b + i * DIM, ybuf);
        gemm_tn<128><<<dim3(52, 18), 256, 0, stream>>>(ybuf, wT, bqkv + i * QKVD,
                                                       ROWS, QKVD, DIM, 0,
                                                       qkvb, nullptr, nullptr);
        attn_scores<<<dim3(13, HEADS, BATCH), 64, 0, stream>>>(qkvb, pbuf);
        attn_pv<<<dim3(HEADS, BATCH), 256, 0, stream>>>(pbuf, qkvb, ybuf);
        gemm_tn<64><<<dim3(104, 6), 256, 0, stream>>>(ybuf, wT + 1769472, bo + i * DIM,
                                                      ROWS, DIM, DIM, 1,
                                                      nullptr, hbuf, nullptr);
        ln_bf16<<<dim3(ROWS), 256, 0, stream>>>(hbuf, ln2g + i * DIM, ln2b + i * DIM, ybuf);
        gemm_tn<128><<<dim3(52, 24), 256, 0, stream>>>(ybuf, wT + 2359296, b1 + i * MLPD,
                                                       ROWS, MLPD, DIM, 2,
                                                       m1buf, nullptr, nullptr);
        gemm_tn<64><<<dim3(104, 6), 256, 0, stream>>>(m1buf, wT + 4718592, b2 + i * DIM,
                                                      ROWS, DIM, MLPD, 1,
                                                      nullptr, hbuf, nullptr);
    }
    head_kernel<<<dim3(BATCH), 256, 0, stream>>>(hbuf, lnpg, lnpb, headW, headB, out);
}

// Round 3
// 3260.456 us; speedup vs baseline: 2.9509x; 1.1472x over previous
//
#include <hip/hip_runtime.h>
#include <hip/hip_bf16.h>

// ---------------- ViT-B/16 forward, MI355X round 3 ----------------
// vs round 2:
//  - GEMM: BK=64 (half the barriers), both-sides XOR swizzle (conflict-free
//    ds_read_b128) with pre-swizzled global_load_lds source (rule #21)
//  - fused attention (scores+softmax+PV, P in swizzled per-wave LDS, no HBM P)
//  - MFMA head (LN-cls -> padded bf16, headW -> bf16 [1024][768], gemm mode 4)

typedef __attribute__((ext_vector_type(8))) short short8;
typedef __attribute__((ext_vector_type(4))) float f32x4;
typedef __attribute__((ext_vector_type(4))) unsigned short us4;

#define MFMA16(a, b, c) __builtin_amdgcn_mfma_f32_16x16x32_bf16(a, b, c, 0, 0, 0)

#define BATCH 32
#define SEQ 197
#define SPAD 208          // 13 * 16
#define DIM 768
#define HEADS 12
#define DKH 64
#define MLPD 3072
#define NCLS 1000
#define NPATCH 196
#define PDIM 768
#define QKVD 2304
#define ROWS (BATCH * SPAD)   // 6656 = 52*128 = 104*64

static __device__ __forceinline__ unsigned short f2bf(float f) {
    unsigned int u = __builtin_bit_cast(unsigned int, f);
    u += 0x7fffu + ((u >> 16) & 1u);             // RNE
    return (unsigned short)(u >> 16);
}

__device__ __forceinline__ void gload16(const void* g, void* l) {
    __builtin_amdgcn_global_load_lds(
        (const __attribute__((address_space(1))) void*)g,
        (__attribute__((address_space(3))) void*)l, 16, 0, 0);
}

// ---------------- patch extraction: x[B,3,224,224] -> patches bf16 [B,196,768]
__global__ __launch_bounds__(256) void patchify(const float* __restrict__ x,
                                                unsigned short* __restrict__ out) {
    int i = blockIdx.x * 256 + threadIdx.x;
    if (i >= BATCH * NPATCH * PDIM) return;
    int b = i / (NPATCH * PDIM);
    int f = i % (NPATCH * PDIM);
    int c = f / 50176, r = f % 50176;
    int gy = r / 3584, r2 = r % 3584;
    int gx = r2 >> 8, r3 = r2 & 255;
    int py = r3 >> 4, px = r3 & 15;
    float v = x[(((size_t)b * 3 + c) * 224 + gy * 16 + py) * 224 + gx * 16 + px];
    out[i] = f2bf(v);
}

// row 0 (cls + pos) and zero pad rows 197..207 of the fp32 residual stream
__global__ __launch_bounds__(256) void embed_misc(const float* __restrict__ cls,
                                                  const float* __restrict__ pos,
                                                  float* __restrict__ h) {
    int b = blockIdx.x, t = threadIdx.x;
    float* hb = h + (size_t)b * SPAD * DIM;
    for (int d = t; d < DIM; d += 256) hb[d] = cls[d] + pos[d];
    for (int i = t; i < (SPAD - SEQ) * DIM; i += 256) hb[SEQ * DIM + i] = 0.f;
}

// ---------------- transpose-convert: src fp32 [K,N] -> dst bf16 [N,K] (32x32 tiles)
__global__ __launch_bounds__(256) void tconv(const float* __restrict__ src,
                                             unsigned short* __restrict__ dst,
                                             int K, int N) {
    __shared__ float tile[32][33];
    int tn = blockIdx.x, tk = blockIdx.y;
    int t = threadIdx.x, r = t >> 3, c4 = (t & 7) << 2;
    float4 v = *reinterpret_cast<const float4*>(&src[(size_t)(tk * 32 + r) * N + tn * 32 + c4]);
    tile[r][c4 + 0] = v.x; tile[r][c4 + 1] = v.y;
    tile[r][c4 + 2] = v.z; tile[r][c4 + 3] = v.w;
    __syncthreads();
    us4 o = { f2bf(tile[c4 + 0][r]), f2bf(tile[c4 + 1][r]),
              f2bf(tile[c4 + 2][r]), f2bf(tile[c4 + 3][r]) };
    *reinterpret_cast<us4*>(&dst[(size_t)(tn * 32 + r) * K + tk * 32 + c4]) = o;
}

// headW fp32 [768,1000] -> hwT bf16 [1024,768], cols >=1000 zero
__global__ __launch_bounds__(256) void hconv(const float* __restrict__ src,
                                             unsigned short* __restrict__ dst) {
    __shared__ float tile[32][33];
    int tn = blockIdx.x, tk = blockIdx.y;
    int t = threadIdx.x, r = t >> 3, c4 = (t & 7) << 2;
#pragma unroll
    for (int i = 0; i < 4; ++i) {
        int c = tn * 32 + c4 + i;
        tile[r][c4 + i] = (c < NCLS) ? src[(size_t)(tk * 32 + r) * NCLS + c] : 0.f;
    }
    __syncthreads();
    us4 o = { f2bf(tile[c4 + 0][r]), f2bf(tile[c4 + 1][r]),
              f2bf(tile[c4 + 2][r]), f2bf(tile[c4 + 3][r]) };
    *reinterpret_cast<us4*>(&dst[(size_t)(tn * 32 + r) * 768 + tk * 32 + c4]) = o;
}

// ---------------- fused per-layer weight conversion into wT region:
//   [0)        qkvT  [2304][768]
//   [1769472)  oT    [768][768]
//   [2359296)  w1T   [3072][768]
//   [4718592)  w2T   [768][3072]
__global__ __launch_bounds__(256) void wconvert(const float* __restrict__ q,
                                                const float* __restrict__ k,
                                                const float* __restrict__ v,
                                                const float* __restrict__ o,
                                                const float* __restrict__ w1,
                                                const float* __restrict__ w2,
                                                unsigned short* __restrict__ wT) {
    __shared__ float tile[32][33];
    int tb = blockIdx.x;
    const float* src; unsigned short* dst; int K, N;
    if (tb < 2304) {
        K = 768; N = 768;
        int m = tb / 576; tb -= m * 576;
        src = (m == 0) ? q : (m == 1) ? k : (m == 2) ? v : o;
        dst = wT + (m < 3 ? (size_t)m * 589824 : (size_t)1769472);
    } else if (tb < 4608) {
        tb -= 2304; K = 768; N = 3072; src = w1; dst = wT + 2359296;
    } else {
        tb -= 4608; K = 3072; N = 768; src = w2; dst = wT + 4718592;
    }
    int TN = N >> 5;
    int tn = tb % TN, tk = tb / TN;
    int t = threadIdx.x, r = t >> 3, c4 = (t & 7) << 2;
    float4 vv = *reinterpret_cast<const float4*>(&src[(size_t)(tk * 32 + r) * N + tn * 32 + c4]);
    tile[r][c4 + 0] = vv.x; tile[r][c4 + 1] = vv.y;
    tile[r][c4 + 2] = vv.z; tile[r][c4 + 3] = vv.w;
    __syncthreads();
    us4 ov = { f2bf(tile[c4 + 0][r]), f2bf(tile[c4 + 1][r]),
               f2bf(tile[c4 + 2][r]), f2bf(tile[c4 + 3][r]) };
    *reinterpret_cast<us4*>(&dst[(size_t)(tn * 32 + r) * K + tk * 32 + c4]) = ov;
}

// pack per-layer qkv bias: bqkv[12][2304]
__global__ __launch_bounds__(256) void pack_bias(const float* __restrict__ bq,
                                                 const float* __restrict__ bk,
                                                 const float* __restrict__ bv,
                                                 float* __restrict__ dst) {
    int i = blockIdx.x * 256 + threadIdx.x;
    if (i >= 12 * QKVD) return;
    int l = i / QKVD, c = i % QKVD;
    float v = (c < 768) ? bq[l * 768 + c]
            : (c < 1536) ? bk[l * 768 + c - 768]
                         : bv[l * 768 + c - 1536];
    dst[i] = v;
}

// ---------------- GEMM: C[M,N] = A bf16[M,K] @ Bt bf16[N,K]^T + bias
// BM x 128 tile, BK=64, 4 waves. global_load_lds(16B) with PRE-SWIZZLED source;
// ds_read_b128 with matching XOR swizzle -> conflict-free (rule #21).
// mode 0: bf16 out  1: outf += (residual)  2: gelu->bf16  3: patch embed(+pos)
// mode 4: head fp32 out guarded to [32,NCLS], bias via pos ptr
template <int BM>
__global__ __launch_bounds__(256) void gemm_tn(
    const unsigned short* __restrict__ A, const unsigned short* __restrict__ Bt,
    const float* __restrict__ bias, int M, int N, int K, int mode,
    unsigned short* __restrict__ outb, float* __restrict__ outf,
    const float* __restrict__ pos) {
    constexpr int MFRAG = BM / 32;        // 4 (BM=128) or 2 (BM=64)
    constexpr int ACH = BM / 8;           // A chunks (1KB = 8 rows x 128B)
    constexpr int TOT = ACH + 16;         // + B chunks (128 rows)
    constexpr int CPW = TOT / 4;          // chunks per wave
    __shared__ unsigned short Alds[BM * 64];
    __shared__ unsigned short Blds[128 * 64];
    const int tid = threadIdx.x, lane = tid & 63, wid = tid >> 6;
    const int row0 = blockIdx.x * BM, col0 = blockIdx.y * 128;
    const int wm = (wid >> 1) * (BM / 2), wn = (wid & 1) * 64;
    const int lr = lane & 15, lg = lane >> 4;
    const int ric = lane >> 3;            // row in chunk 0..7
    const int sswz = (lane & 7) ^ ric;    // pre-swizzled 16B slot in source

    const char* gptr[CPW];
    char* lptr[CPW];
#pragma unroll
    for (int j = 0; j < CPW; ++j) {
        int cc = wid * CPW + j;
        if (cc < ACH) {
            int grow = row0 + cc * 8 + ric;
            gptr[j] = (const char*)A + (size_t)grow * K * 2 + sswz * 16;
            lptr[j] = (char*)Alds + cc * 1024;
        } else {
            int grow = col0 + (cc - ACH) * 8 + ric;
            gptr[j] = (const char*)Bt + (size_t)grow * K * 2 + sswz * 16;
            lptr[j] = (char*)Blds + (cc - ACH) * 1024;
        }
    }

    f32x4 acc[MFRAG][4];
#pragma unroll
    for (int m = 0; m < MFRAG; ++m)
#pragma unroll
        for (int n = 0; n < 4; ++n) acc[m][n] = (f32x4){0.f, 0.f, 0.f, 0.f};

    const int rsw = lr & 7;               // read-side row XOR operand
    for (int ks = 0; ks < K; ks += 64) {
        __syncthreads();
#pragma unroll
        for (int j = 0; j < CPW; ++j) {
            gload16(gptr[j], lptr[j]);
            gptr[j] += 128;
        }
        __syncthreads();
        short8 af[MFRAG][2], bfr[4][2];
#pragma unroll
        for (int m = 0; m < MFRAG; ++m)
#pragma unroll
            for (int kk = 0; kk < 2; ++kk)
                af[m][kk] = *reinterpret_cast<const short8*>(
                    &Alds[(wm + m * 16 + lr) * 64 + (((kk * 4 + lg) ^ rsw) << 3)]);
#pragma unroll
        for (int n = 0; n < 4; ++n)
#pragma unroll
            for (int kk = 0; kk < 2; ++kk)
                bfr[n][kk] = *reinterpret_cast<const short8*>(
                    &Blds[(wn + n * 16 + lr) * 64 + (((kk * 4 + lg) ^ rsw) << 3)]);
#pragma unroll
        for (int m = 0; m < MFRAG; ++m)
#pragma unroll
            for (int n = 0; n < 4; ++n) {
                acc[m][n] = MFMA16(af[m][0], bfr[n][0], acc[m][n]);
                acc[m][n] = MFMA16(af[m][1], bfr[n][1], acc[m][n]);
            }
    }
    // epilogue — C/D layout: col = lane&15, row = (lane>>4)*4 + reg
#pragma unroll
    for (int m = 0; m < MFRAG; ++m) {
#pragma unroll
        for (int n = 0; n < 4; ++n) {
            int gcol = col0 + wn + n * 16 + lr;
            float bv = bias ? bias[gcol] : 0.f;
#pragma unroll
            for (int i = 0; i < 4; ++i) {
                int grow = row0 + wm + m * 16 + lg * 4 + i;
                float v = acc[m][n][i] + bv;
                if (mode == 0) {
                    outb[(size_t)grow * N + gcol] = f2bf(v);
                } else if (mode == 1) {
                    outf[(size_t)grow * N + gcol] += v;
                } else if (mode == 2) {
                    v = 0.5f * v * (1.f + erff(v * 0.70710678118654752f));
                    outb[(size_t)grow * N + gcol] = f2bf(v);
                } else if (mode == 3) {  // patch embed rows -> h[b, 1+n, :] + pos
                    int pb = grow / NPATCH, pn = grow % NPATCH;
                    size_t o = ((size_t)pb * SPAD + 1 + pn) * DIM + gcol;
                    outf[o] = v + pos[(size_t)(1 + pn) * DIM + gcol];
                } else {                 // mode 4: head
                    if (grow < BATCH && gcol < NCLS)
                        outf[(size_t)grow * NCLS + gcol] = v + pos[gcol];
                }
            }
        }
    }
}

// ---------------- LayerNorm fp32 -> bf16, one block per row (D=768)
__global__ __launch_bounds__(256) void ln_bf16(const float* __restrict__ x,
                                               const float* __restrict__ g,
                                               const float* __restrict__ b,
                                               unsigned short* __restrict__ y) {
    __shared__ float red[8];
    int row = blockIdx.x, t = threadIdx.x;
    const float* xr = x + (size_t)row * DIM;
    float v0 = xr[t], v1 = xr[t + 256], v2 = xr[t + 512];
    float s = v0 + v1 + v2, sq = v0 * v0 + v1 * v1 + v2 * v2;
#pragma unroll
    for (int off = 1; off < 64; off <<= 1) {
        s += __shfl_xor(s, off);
        sq += __shfl_xor(sq, off);
    }
    if ((t & 63) == 0) { red[t >> 6] = s; red[4 + (t >> 6)] = sq; }
    __syncthreads();
    s = red[0] + red[1] + red[2] + red[3];
    sq = red[4] + red[5] + red[6] + red[7];
    float mu = s * (1.f / 768.f);
    float var = fmaxf(sq * (1.f / 768.f) - mu * mu, 0.f);
    float rs = rsqrtf(var + 1e-5f);
    unsigned short* yr = y + (size_t)row * DIM;
    yr[t]       = f2bf((v0 - mu) * rs * g[t] + b[t]);
    yr[t + 256] = f2bf((v1 - mu) * rs * g[t + 256] + b[t + 256]);
    yr[t + 512] = f2bf((v2 - mu) * rs * g[t + 512] + b[t + 512]);
}

// LN of cls rows only -> clsbuf bf16 [64][768] (rows 32..63 zero)
__global__ __launch_bounds__(256) void ln_cls(const float* __restrict__ x,
                                              const float* __restrict__ g,
                                              const float* __restrict__ b,
                                              unsigned short* __restrict__ y) {
    __shared__ float red[8];
    int bb = blockIdx.x, t = threadIdx.x;
    unsigned short* yr = y + (size_t)bb * DIM;
    if (bb >= BATCH) {
        yr[t] = 0; yr[t + 256] = 0; yr[t + 512] = 0;
        return;
    }
    const float* xr = x + (size_t)bb * SPAD * DIM;
    float v0 = xr[t], v1 = xr[t + 256], v2 = xr[t + 512];
    float s = v0 + v1 + v2, sq = v0 * v0 + v1 * v1 + v2 * v2;
#pragma unroll
    for (int off = 1; off < 64; off <<= 1) {
        s += __shfl_xor(s, off);
        sq += __shfl_xor(sq, off);
    }
    if ((t & 63) == 0) { red[t >> 6] = s; red[4 + (t >> 6)] = sq; }
    __syncthreads();
    s = red[0] + red[1] + red[2] + red[3];
    sq = red[4] + red[5] + red[6] + red[7];
    float mu = s * (1.f / 768.f);
    float var = fmaxf(sq * (1.f / 768.f) - mu * mu, 0.f);
    float rs = rsqrtf(var + 1e-5f);
    yr[t]       = f2bf((v0 - mu) * rs * g[t] + b[t]);
    yr[t + 256] = f2bf((v1 - mu) * rs * g[t + 256] + b[t + 256]);
    yr[t + 512] = f2bf((v2 - mu) * rs * g[t + 512] + b[t + 512]);
}

// ---------------- fused attention: per (h,b) block, 4 waves.
// Each wave owns q-tiles qt = wid, wid+4, ... : QK^T (MFMA) -> in-reg softmax
// -> P into per-wave swizzled LDS slice -> PV (MFMA) -> att bf16.
__global__ __launch_bounds__(256) void attn_fused(const unsigned short* __restrict__ qkv,
                                                  unsigned short* __restrict__ att) {
    __shared__ unsigned short Vlds[64][232];       // [d][k] 464B stride
    __shared__ unsigned short Plds[4][16 * 256];   // per-wave [16 q][256 k], swizzled
    int h = blockIdx.x, b = blockIdx.y, tid = threadIdx.x;
    // stage V (fused qkv col 1536+) transposed into LDS
    for (int idx = tid; idx < SPAD * 8; idx += 256) {
        int s = idx >> 3, dc = (idx & 7) << 3;
        uint4 w = *reinterpret_cast<const uint4*>(
            &qkv[((size_t)b * SPAD + s) * QKVD + 1536 + h * DKH + dc]);
        const unsigned short* pe = reinterpret_cast<const unsigned short*>(&w);
#pragma unroll
        for (int i = 0; i < 8; ++i) Vlds[dc + i][s] = pe[i];
    }
    for (int i = tid; i < 64 * 24; i += 256) Vlds[i / 24][208 + (i % 24)] = 0;
    __syncthreads();

    int wid = tid >> 6, lane = tid & 63, lr = lane & 15, lg = lane >> 4;
    unsigned short* Pw = &Plds[wid][0];
    const short8 zero8 = {0, 0, 0, 0, 0, 0, 0, 0};

    for (int qt = wid; qt < 13; qt += 4) {
        // ---- scores: S[q,k] for 16 q-rows x 208 k-tokens
        size_t qoff = ((size_t)b * SPAD + qt * 16 + lr) * QKVD + h * DKH + lg * 8;
        short8 qf0 = *reinterpret_cast<const short8*>(&qkv[qoff]);
        short8 qf1 = *reinterpret_cast<const short8*>(&qkv[qoff + 32]);
        f32x4 acc[13];
#pragma unroll
        for (int kt = 0; kt < 13; ++kt) {
            size_t koff = ((size_t)b * SPAD + kt * 16 + lr) * QKVD + 768 + h * DKH + lg * 8;
            short8 kf0 = *reinterpret_cast<const short8*>(&qkv[koff]);
            short8 kf1 = *reinterpret_cast<const short8*>(&qkv[koff + 32]);
            f32x4 a = (f32x4){0.f, 0.f, 0.f, 0.f};
            a = MFMA16(qf0, kf0, a);
            a = MFMA16(qf1, kf1, a);
            acc[kt] = a;
        }
#pragma unroll
        for (int kt = 0; kt < 13; ++kt)
#pragma unroll
            for (int r = 0; r < 4; ++r) acc[kt][r] *= 0.125f;
        if (lr >= 5) {
#pragma unroll
            for (int r = 0; r < 4; ++r) acc[12][r] = -1e30f;   // tokens >=197
        }
        float mx[4] = {-1e30f, -1e30f, -1e30f, -1e30f};
#pragma unroll
        for (int kt = 0; kt < 13; ++kt)
#pragma unroll
            for (int r = 0; r < 4; ++r) mx[r] = fmaxf(mx[r], acc[kt][r]);
#pragma unroll
        for (int r = 0; r < 4; ++r) {
            mx[r] = fmaxf(mx[r], __shfl_xor(mx[r], 1));
            mx[r] = fmaxf(mx[r], __shfl_xor(mx[r], 2));
            mx[r] = fmaxf(mx[r], __shfl_xor(mx[r], 4));
            mx[r] = fmaxf(mx[r], __shfl_xor(mx[r], 8));
        }
        float sm[4] = {0.f, 0.f, 0.f, 0.f};
#pragma unroll
        for (int kt = 0; kt < 13; ++kt)
#pragma unroll
            for (int r = 0; r < 4; ++r) {
                float e = __expf(acc[kt][r] - mx[r]);
                acc[kt][r] = e;
                sm[r] += e;
            }
#pragma unroll
        for (int r = 0; r < 4; ++r) {
            sm[r] += __shfl_xor(sm[r], 1);
            sm[r] += __shfl_xor(sm[r], 2);
            sm[r] += __shfl_xor(sm[r], 4);
            sm[r] += __shfl_xor(sm[r], 8);
        }
        // ---- P -> swizzled LDS: (row, col) at row*256 + ((slot^ (row&7))<<3 | col&7)
#pragma unroll
        for (int r = 0; r < 4; ++r) {
            int row = lg * 4 + r;
            float inv = 1.f / sm[r];
#pragma unroll
            for (int kt = 0; kt < 13; ++kt) {
                int col = kt * 16 + lr;
                int idx = row * 256 + ((((col >> 3) ^ (row & 7)) << 3) | (col & 7));
                Pw[idx] = f2bf(acc[kt][r] * inv);
            }
        }
        if (lr < 6) {   // zero slots 26..31 (cols 208..255) of each owned row
            int s = 26 + lr;
#pragma unroll
            for (int r = 0; r < 4; ++r) {
                int row = lg * 4 + r;
                *reinterpret_cast<short8*>(&Pw[row * 256 + ((s ^ (row & 7)) << 3)]) = zero8;
            }
        }
        // ---- PV: D[q,d] = sum_k P[q,k] V[k,d]
        int rsw = lr & 7;
#pragma unroll
        for (int dt = 0; dt < 4; ++dt) {
            f32x4 a = (f32x4){0.f, 0.f, 0.f, 0.f};
#pragma unroll
            for (int kk = 0; kk < 7; ++kk) {
                short8 af = *reinterpret_cast<const short8*>(
                    &Pw[lr * 256 + (((kk * 4 + lg) ^ rsw) << 3)]);
                short8 bfr = *reinterpret_cast<const short8*>(
                    &Vlds[dt * 16 + lr][kk * 32 + lg * 8]);
                a = MFMA16(af, bfr, a);
            }
#pragma unroll
            for (int i = 0; i < 4; ++i) {
                int s = qt * 16 + lg * 4 + i;
                att[((size_t)b * SPAD + s) * DIM + h * DKH + dt * 16 + lr] = f2bf(a[i]);
            }
        }
    }
}

extern "C" void kernel_launch(void* const* d_in, const int* in_sizes, int n_in,
                              void* d_out, int out_size, void* d_ws, size_t ws_size,
                              hipStream_t stream) {
    const float* x      = (const float*)d_in[0];
    const float* patchW = (const float*)d_in[1];
    const float* patchB = (const float*)d_in[2];
    const float* clstok = (const float*)d_in[3];
    const float* pose   = (const float*)d_in[4];
    const float* Wq = (const float*)d_in[5];
    const float* bq = (const float*)d_in[6];
    const float* Wk = (const float*)d_in[7];
    const float* bk = (const float*)d_in[8];
    const float* Wv = (const float*)d_in[9];
    const float* bv = (const float*)d_in[10];
    const float* Wo = (const float*)d_in[11];
    const float* bo = (const float*)d_in[12];
    const float* ln1g = (const float*)d_in[13];
    const float* ln1b = (const float*)d_in[14];
    const float* ln2g = (const float*)d_in[15];
    const float* ln2b = (const float*)d_in[16];
    const float* W1 = (const float*)d_in[17];
    const float* b1 = (const float*)d_in[18];
    const float* W2 = (const float*)d_in[19];
    const float* b2 = (const float*)d_in[20];
    const float* lnpg = (const float*)d_in[21];
    const float* lnpb = (const float*)d_in[22];
    const float* headW = (const float*)d_in[23];
    const float* headB = (const float*)d_in[24];
    float* out = (float*)d_out;

    // workspace layout (~116.6 MB):
    constexpr size_t SZ_H   = (size_t)ROWS * DIM * 4;     // fp32 residual
    constexpr size_t SZ_QKV = (size_t)ROWS * QKVD * 2;    // fused qkv bf16
    constexpr size_t SZ_Y   = (size_t)ROWS * DIM * 2;     // ln out / att bf16
    constexpr size_t SZ_M1  = (size_t)ROWS * MLPD * 2;    // mlp mid / patches / head
    constexpr size_t SZ_WT  = (size_t)7077888 * 2;        // per-layer bf16 weightsT
    char* w = (char*)d_ws;
    float* hbuf            = (float*)w;
    unsigned short* qkvb   = (unsigned short*)(w + SZ_H);
    unsigned short* ybuf   = (unsigned short*)(w + SZ_H + SZ_QKV);
    unsigned short* m1buf  = (unsigned short*)(w + SZ_H + SZ_QKV + SZ_Y);
    unsigned short* wT     = (unsigned short*)(w + SZ_H + SZ_QKV + SZ_Y + SZ_M1);
    float* bqkv            = (float*)(w + SZ_H + SZ_QKV + SZ_Y + SZ_M1 + SZ_WT);
    unsigned short* patches = m1buf;                      // embed phase
    unsigned short* clsbuf  = m1buf;                      // head phase [64][768]
    unsigned short* hwT     = m1buf + 64 * DIM;           // head phase [1024][768]

    pack_bias<<<dim3(108), 256, 0, stream>>>(bq, bk, bv, bqkv);

    // patch embed
    tconv<<<dim3(24, 24), 256, 0, stream>>>(patchW, wT, PDIM, DIM);
    patchify<<<dim3((BATCH * NPATCH * PDIM + 255) / 256), 256, 0, stream>>>(x, patches);
    embed_misc<<<dim3(BATCH), 256, 0, stream>>>(clstok, pose, hbuf);
    gemm_tn<64><<<dim3(98, 6), 256, 0, stream>>>(patches, wT, patchB,
                                                 BATCH * NPATCH, DIM, PDIM, 3,
                                                 nullptr, hbuf, pose);

    for (int i = 0; i < 12; ++i) {
        const size_t wo = (size_t)i * DIM * DIM;
        const size_t wm = (size_t)i * DIM * MLPD;
        wconvert<<<dim3(6912), 256, 0, stream>>>(Wq + wo, Wk + wo, Wv + wo, Wo + wo,
                                                 W1 + wm, W2 + wm, wT);
        ln_bf16<<<dim3(ROWS), 256, 0, stream>>>(hbuf, ln1g + i * DIM, ln1b + i * DIM, ybuf);
        gemm_tn<128><<<dim3(52, 18), 256, 0, stream>>>(ybuf, wT, bqkv + i * QKVD,
                                                       ROWS, QKVD, DIM, 0,
                                                       qkvb, nullptr, nullptr);
        attn_fused<<<dim3(HEADS, BATCH), 256, 0, stream>>>(qkvb, ybuf);
        gemm_tn<64><<<dim3(104, 6), 256, 0, stream>>>(ybuf, wT + 1769472, bo + i * DIM,
                                                      ROWS, DIM, DIM, 1,
                                                      nullptr, hbuf, nullptr);
        ln_bf16<<<dim3(ROWS), 256, 0, stream>>>(hbuf, ln2g + i * DIM, ln2b + i * DIM, ybuf);
        gemm_tn<128><<<dim3(52, 24), 256, 0, stream>>>(ybuf, wT + 2359296, b1 + i * MLPD,
                                                       ROWS, MLPD, DIM, 2,
                                                       m1buf, nullptr, nullptr);
        gemm_tn<64><<<dim3(104, 6), 256, 0, stream>>>(m1buf, wT + 4718592, b2 + i * DIM,
                                                      ROWS, DIM, MLPD, 1,
                                                      nullptr, hbuf, nullptr);
    }
    // head: LN cls rows -> clsbuf [64][768]; headW -> hwT [1024][768]; MFMA GEMM
    ln_cls<<<dim3(64), 256, 0, stream>>>(hbuf, lnpg, lnpb, clsbuf);
    hconv<<<dim3(32, 24), 256, 0, stream>>>(headW, hwT);
    gemm_tn<64><<<dim3(1, 8), 256, 0, stream>>>(clsbuf, hwT, nullptr,
                                                64, 1024, DIM, 4,
                                                nullptr, out, headB);
}